// Round 9
// baseline (231.787 us; speedup 1.0000x reference)
//
#include <hip/hip_runtime.h>
#include <math.h>

// CapsuleLinear dynamic routing, `priors` never materialized.
//   s[b,o,i]   = sum_n prob[b,o,n] * x[b,n,i]
//   out[b,o,l] = sum_i W[o,l,i] * s[b,o,i]
//   logits[b,o,n] = x[b,n,:] . T[b,o,:],  T accumulates t_r[o,i] = sum_l W[o,l,i]*v_r[o,l]
//
// R9: R8 post-mortem — 32-block fusion starved the machine (2.9% occupancy,
// 147 us); R7's chain structure stands but its pass kernels hide latency with
// only 2 waves/SIMD (grid- and LDS-capped). This round raises pass occupancy:
//   - NCHUNK 16 -> 32: 1024 blocks, 4 blocks/CU, 4 waves/SIMD (2x hiding).
//   - flush via LDS atomicAdd (ds_add_f32) into a stride-33 accumulator
//     ((o+i)%32 banks: conflict-free): pass LDS 36 KB -> 8.5 KB.
//   - kB: same redundant vt-reduce (L2-warm part, now 32 slabs, unroll-8
//     keeps loads in flight) + T1 in LDS + pass2 -> part2 (race-free).
//   - k_init (R0-proven) and kC (R6-proven, 32 slabs) unchanged otherwise.
// Chain: k_init -> k_pass1 -> kB -> kC. XCD-aware decode: xcd=d&7 gets 4
// whole batches (x slab 588 KB + part 1 MB per XCD L2).

#define N_B      32
#define IN_CAPS  1152
#define IN_LEN   32
#define OUT_CAPS 64
#define OUT_LEN  32

#define NCHUNK 32                    // n-chunks per batch -> 32*32 = 1024 blocks
#define NPB    (IN_CAPS / NCHUNK)    // 36 n per block
#define PASS_WAVES 4                 // 256-thread blocks
#define NPW    (NPB / PASS_WAVES)    // 9 n per wave
#define TSTR   36                    // padded T_lds row stride (f4-aligned)
#define SSTR   33                    // s_red row stride: bank (o+i)%32, conflict-free

// XCD-aware decode of blockIdx.x -> (b,c): presumed round-robin XCD = d&7;
// each XCD gets 4 whole batches. Pure perf heuristic, bijective (1024%8==0).
#define DECODE_BC(d, b, c) \
    const int _slot = (d) >> 3; \
    const int b = ((d) & 7) * 4 + (_slot >> 5); \
    const int c = _slot & 31;

// DPP helper: butterfly step, all lanes valid.
#define DPPV(v, ctrl) \
    __int_as_float(__builtin_amdgcn_update_dpp(0, __float_as_int(v), ctrl, 0xF, 0xF, true))

__device__ __forceinline__ float wave_max(float v) {
    v = fmaxf(v, DPPV(v, 0xB1));         // quad_perm xor1
    v = fmaxf(v, DPPV(v, 0x4E));         // quad_perm xor2
    v = fmaxf(v, DPPV(v, 0x141));        // row_half_mirror (xor4 within 8)
    v = fmaxf(v, DPPV(v, 0x140));        // row_mirror (xor8 within 16)
    v = fmaxf(v, __shfl_xor(v, 16, 64)); // cross-row (proven path)
    v = fmaxf(v, __shfl_xor(v, 32, 64));
    return v;
}
__device__ __forceinline__ float wave_sum(float v) {
    v += DPPV(v, 0xB1);
    v += DPPV(v, 0x4E);
    v += DPPV(v, 0x141);
    v += DPPV(v, 0x140);
    v += __shfl_xor(v, 16, 64);
    v += __shfl_xor(v, 32, 64);
    return v;
}

// ---------------------------------------------------------------------------
// Pass body (R4-proven math): logits from pinned t[] vs broadcast x rows,
// DPP+shfl softmax over 64 lanes (= o), s accumulate; flush via LDS atomics
// into s_red (stride 33), then coalesced copy to part[b,c].
// ---------------------------------------------------------------------------
__device__ __forceinline__ void pass_atomic(const float* __restrict__ x,
                                            const float* T_row_src, int t_stride,
                                            float* s_red,
                                            float* __restrict__ part_out,
                                            int b, int c, int tid, int lane, int wave) {
    // zero the block accumulator
    for (int e = tid; e < OUT_CAPS * SSTR; e += 256) s_red[e] = 0.f;

    float t[IN_LEN];
    {
#pragma unroll
        for (int q = 0; q < 8; ++q) {
            const float4 v = *(const float4*)&T_row_src[lane * t_stride + q * 4];
            t[4 * q] = v.x; t[4 * q + 1] = v.y; t[4 * q + 2] = v.z; t[4 * q + 3] = v.w;
        }
    }
    asm volatile("" : "+v"(t[0]), "+v"(t[1]), "+v"(t[2]), "+v"(t[3]),
                      "+v"(t[4]), "+v"(t[5]), "+v"(t[6]), "+v"(t[7]),
                      "+v"(t[8]), "+v"(t[9]), "+v"(t[10]), "+v"(t[11]),
                      "+v"(t[12]), "+v"(t[13]), "+v"(t[14]), "+v"(t[15]));
    asm volatile("" : "+v"(t[16]), "+v"(t[17]), "+v"(t[18]), "+v"(t[19]),
                      "+v"(t[20]), "+v"(t[21]), "+v"(t[22]), "+v"(t[23]),
                      "+v"(t[24]), "+v"(t[25]), "+v"(t[26]), "+v"(t[27]),
                      "+v"(t[28]), "+v"(t[29]), "+v"(t[30]), "+v"(t[31]));

    float s[IN_LEN];
#pragma unroll
    for (int i = 0; i < IN_LEN; ++i) s[i] = 0.f;

    const float* xw = x + ((size_t)b * IN_CAPS + c * NPB + wave * NPW) * IN_LEN;

#define L4(acc, R, k) \
    acc = fmaf((R).x, t[k],     acc); acc = fmaf((R).y, t[k + 1], acc); \
    acc = fmaf((R).z, t[k + 2], acc); acc = fmaf((R).w, t[k + 3], acc);
#define S4(R, k) \
    s[k]     = fmaf(prob, (R).x, s[k]);     s[k + 1] = fmaf(prob, (R).y, s[k + 1]); \
    s[k + 2] = fmaf(prob, (R).z, s[k + 2]); s[k + 3] = fmaf(prob, (R).w, s[k + 3]);

#pragma unroll
    for (int j = 0; j < NPW; ++j) {
        const float4* xr = (const float4*)(xw + j * IN_LEN);  // wave-uniform addr
        const float4 r0 = xr[0], r1 = xr[1], r2 = xr[2], r3 = xr[3],
                     r4 = xr[4], r5 = xr[5], r6 = xr[6], r7 = xr[7];

        float l0 = 0.f, l1 = 0.f, l2 = 0.f, l3 = 0.f;
        L4(l0, r0, 0)  L4(l1, r1, 4)  L4(l2, r2, 8)  L4(l3, r3, 12)
        L4(l0, r4, 16) L4(l1, r5, 20) L4(l2, r6, 24) L4(l3, r7, 28)
        const float logit = (l0 + l1) + (l2 + l3);

        const float m = wave_max(logit);
        const float p = __expf(logit - m);
        const float S = wave_sum(p);
        const float prob = p * __builtin_amdgcn_rcpf(S);

        S4(r0, 0)  S4(r1, 4)  S4(r2, 8)  S4(r3, 12)
        S4(r4, 16) S4(r5, 20) S4(r6, 24) S4(r7, 28)
    }
#undef L4
#undef S4

    __syncthreads();                     // zeroing complete everywhere
    {
        float* row = s_red + lane * SSTR;  // bank (lane+i)%32: conflict-free
#pragma unroll
        for (int i = 0; i < IN_LEN; ++i) atomicAdd(&row[i], s[i]);
    }
    __syncthreads();                     // all wave partials accumulated

    // coalesced copy to part[b,c]
    {
        float* pb = part_out + ((size_t)b * NCHUNK + c) * OUT_CAPS * IN_LEN;
        for (int e = tid; e < OUT_CAPS * IN_LEN; e += 256)
            pb[e] = s_red[(e >> 5) * SSTR + (e & 31)];
    }
}

// ---------------------------------------------------------------------------
// k_init: s0 = (1/64) sum_n x[b,n,:]; u = W@s0; squash; T = W^T@v0.
// 32 blocks — the single cold-HBM read of x. (R0-proven)
// ---------------------------------------------------------------------------
__global__ __launch_bounds__(256) void k_init(const float* __restrict__ x,
                                              const float* __restrict__ W,
                                              float* __restrict__ T) {
    const int b   = blockIdx.x;
    const int tid = threadIdx.x;
    const float* xb = x + (size_t)b * IN_CAPS * IN_LEN;

    __shared__ float4 red4[32][8];
    {
        const int q = tid & 7;
        const int g = tid >> 3;
        float4 acc = make_float4(0.f, 0.f, 0.f, 0.f);
        for (int n = g; n < IN_CAPS; n += 32) {
            const float4 v = *(const float4*)(xb + n * IN_LEN + q * 4);
            acc.x += v.x; acc.y += v.y; acc.z += v.z; acc.w += v.w;
        }
        red4[g][q] = acc;
    }
    __syncthreads();
    __shared__ float s0[IN_LEN];
    if (tid < 8) {
        float4 v = make_float4(0.f, 0.f, 0.f, 0.f);
        for (int g = 0; g < 32; ++g) {
            const float4 r = red4[g][tid];
            v.x += r.x; v.y += r.y; v.z += r.z; v.w += r.w;
        }
        const float inv = 1.f / 64.f;   // uniform softmax prob at r=0
        s0[tid * 4 + 0] = v.x * inv;
        s0[tid * 4 + 1] = v.y * inv;
        s0[tid * 4 + 2] = v.z * inv;
        s0[tid * 4 + 3] = v.w * inv;
    }
    __syncthreads();

    __shared__ float u[OUT_CAPS * OUT_LEN];
    for (int e = tid; e < OUT_CAPS * OUT_LEN; e += 256) {
        const float* wrow = W + (size_t)e * IN_LEN;
        float a = 0.f;
#pragma unroll
        for (int i = 0; i < IN_LEN; ++i) a = fmaf(wrow[i], s0[i], a);
        u[e] = a;
    }
    __syncthreads();

    __shared__ float scale[OUT_CAPS];
    if (tid < OUT_CAPS) {
        float ns = 0.f;
#pragma unroll
        for (int l = 0; l < OUT_LEN; ++l) { const float v = u[tid * OUT_LEN + l]; ns = fmaf(v, v, ns); }
        scale[tid] = sqrtf(ns) / (1.f + ns);
    }
    __syncthreads();

    for (int e = tid; e < OUT_CAPS * IN_LEN; e += 256) {
        const int o = e >> 5, i = e & 31;
        float a = 0.f;
#pragma unroll
        for (int l = 0; l < OUT_LEN; ++l)
            a = fmaf(W[((size_t)o * OUT_LEN + l) * IN_LEN + i], u[o * OUT_LEN + l], a);
        T[(size_t)b * OUT_CAPS * IN_LEN + e] = a * scale[o];
    }
}

// ---------------------------------------------------------------------------
// k_pass1: routing iter 1. 1024 blocks, LDS 8.5 KB -> 4 blocks/CU.
// ---------------------------------------------------------------------------
__global__ __launch_bounds__(256, 4) void k_pass1(const float* __restrict__ x,
                                                  const float* __restrict__ T,
                                                  float* __restrict__ part) {
    DECODE_BC(blockIdx.x, b, c)
    const int tid  = threadIdx.x;
    const int lane = tid & 63;
    const int wave = __builtin_amdgcn_readfirstlane(tid >> 6);
    (void)wave;

    __shared__ __align__(16) float s_red[OUT_CAPS * SSTR];   // 8.25 KB

    pass_atomic(x, T + (size_t)b * OUT_CAPS * IN_LEN, IN_LEN,
                s_red, part, b, c, tid, lane, wave);
}

// ---------------------------------------------------------------------------
// kB: redundant vt-reduce (32 slabs of L2-warm part -> s -> u -> squash;
//     T1 = T0 + W^T v1 in LDS), then routing iter 2 -> part2 (race-free).
// ---------------------------------------------------------------------------
__global__ __launch_bounds__(256, 4) void kB(const float* __restrict__ x,
                                             const float* __restrict__ W,
                                             const float* __restrict__ T,
                                             const float* __restrict__ part,
                                             float* __restrict__ part2) {
    DECODE_BC(blockIdx.x, b, c)
    const int tid  = threadIdx.x;
    const int lane = tid & 63;
    const int wave = __builtin_amdgcn_readfirstlane(tid >> 6);

    __shared__ __align__(16) float T_lds[OUT_CAPS * TSTR];   // 9.2 KB
    __shared__ __align__(16) float s_red[OUT_CAPS * SSTR];   // 8.25 KB (pass flush)
    __shared__ __align__(16) float svt[OUT_CAPS * IN_LEN];   // 8 KB (vt reduce)
    __shared__ __align__(16) float uu[OUT_CAPS * OUT_LEN];   // 8 KB
    __shared__ float sc[OUT_CAPS];

    // ---- redundant vt-reduce: 512 f4-lanes x 32 slabs, unroll-8 in flight ----
    {
        const float4* pb4 = (const float4*)(part + (size_t)b * NCHUNK * OUT_CAPS * IN_LEN);
        for (int e = tid; e < OUT_CAPS * IN_LEN / 4; e += 256) {
            float4 acc = make_float4(0.f, 0.f, 0.f, 0.f);
#pragma unroll 8
            for (int cc = 0; cc < NCHUNK; ++cc) {
                const float4 v = pb4[cc * (OUT_CAPS * IN_LEN / 4) + e];
                acc.x += v.x; acc.y += v.y; acc.z += v.z; acc.w += v.w;
            }
            ((float4*)svt)[e] = acc;
        }
    }
    __syncthreads();
    for (int e = tid; e < OUT_CAPS * OUT_LEN; e += 256) {
        const int o = e >> 5;
        const float* wrow = W + (size_t)e * IN_LEN;
        const float* srow = svt + o * IN_LEN;
        float a = 0.f;
#pragma unroll
        for (int i = 0; i < IN_LEN; ++i) a = fmaf(wrow[i], srow[i], a);
        uu[e] = a;
    }
    __syncthreads();
    if (tid < OUT_CAPS) {
        float ns = 0.f;
#pragma unroll
        for (int l = 0; l < OUT_LEN; ++l) { const float v = uu[tid * OUT_LEN + l]; ns = fmaf(v, v, ns); }
        sc[tid] = sqrtf(ns) / (1.f + ns);
    }
    __syncthreads();

    // T1 = T0 + W^T @ (uu * sc)  -> LDS
    for (int e = tid; e < OUT_CAPS * IN_LEN; e += 256) {
        const int o = e >> 5, i = e & 31;
        float a = 0.f;
#pragma unroll
        for (int l = 0; l < OUT_LEN; ++l)
            a = fmaf(W[((size_t)o * OUT_LEN + l) * IN_LEN + i], uu[o * OUT_LEN + l], a);
        T_lds[o * TSTR + i] = T[(size_t)b * OUT_CAPS * IN_LEN + e] + a * sc[o];
    }
    __syncthreads();

    pass_atomic(x, T_lds, TSTR, s_red, part2, b, c, tid, lane, wave);
}

// ---------------------------------------------------------------------------
// kC: final vt, split by o-group. 256 blocks = 32 b x 8 groups of 8 o.
// (R6-proven pattern, 32 slabs)
// ---------------------------------------------------------------------------
__global__ __launch_bounds__(256) void kC(const float* __restrict__ W,
                                          const float* __restrict__ part2,
                                          float* __restrict__ out) {
    const int b   = blockIdx.x >> 3;
    const int og  = blockIdx.x & 7;
    const int tid = threadIdx.x;
    const int ol  = tid >> 5;            // 0..7 local o
    const int i   = tid & 31;            // input index / later l
    const int o   = og * 8 + ol;

    float a = 0.f;
    const float* pb = part2 + (size_t)b * NCHUNK * OUT_CAPS * IN_LEN + o * IN_LEN + i;
#pragma unroll 8
    for (int cc = 0; cc < NCHUNK; ++cc) a += pb[cc * OUT_CAPS * IN_LEN];

    __shared__ float s_lds[8][33];
    s_lds[ol][i] = a;
    __syncthreads();

    const float* wrow = W + ((size_t)o * OUT_LEN + i) * IN_LEN;
    float u = 0.f;
#pragma unroll
    for (int k = 0; k < IN_LEN; ++k) u = fmaf(wrow[k], s_lds[ol][k], u);

    float ns = u * u;
    ns += __shfl_xor(ns, 1, 64);
    ns += __shfl_xor(ns, 2, 64);
    ns += __shfl_xor(ns, 4, 64);
    ns += __shfl_xor(ns, 8, 64);
    ns += __shfl_xor(ns, 16, 64);
    const float scale = sqrtf(ns) / (1.f + ns);

    out[((size_t)b * OUT_CAPS + o) * OUT_LEN + i] = u * scale;
}

extern "C" void kernel_launch(void* const* d_in, const int* in_sizes, int n_in,
                              void* d_out, int out_size, void* d_ws, size_t ws_size,
                              hipStream_t stream) {
    const float* x = (const float*)d_in[0];   // [32,1152,32]
    const float* W = (const float*)d_in[1];   // [64,32,32]
    float* out = (float*)d_out;               // [32,64,32]

    float* T     = (float*)d_ws;                          // 256 KB
    float* part  = T + (size_t)N_B * OUT_CAPS * IN_LEN;   // 8 MB (iter-1 partials)
    float* part2 = part + (size_t)N_B * NCHUNK * OUT_CAPS * IN_LEN; // 8 MB (iter-2)

    k_init <<<N_B,          256, 0, stream>>>(x, W, T);
    k_pass1<<<N_B * NCHUNK, 256, 0, stream>>>(x, T, part);           // routing iter 1
    kB     <<<N_B * NCHUNK, 256, 0, stream>>>(x, W, T, part, part2); // vt1 + iter 2
    kC     <<<N_B * 8,      256, 0, stream>>>(W, part2, out);        // final vt
}

// Round 10
// 202.684 us; speedup vs baseline: 1.1436x; 1.1436x over previous
//
#include <hip/hip_runtime.h>
#include <math.h>

// CapsuleLinear dynamic routing, `priors` never materialized.
//   s[b,o,i]   = sum_n prob[b,o,n] * x[b,n,i]
//   out[b,o,l] = sum_i W[o,l,i] * s[b,o,i]
//   logits[b,o,n] = x[b,n,:] . T[b,o,:],  T accumulates t_r[o,i] = sum_l W[o,l,i]*v_r[o,l]
//
// R10: R9 post-mortem — occupancy push regressed because it multiplied the
// redundant vt-reduce's 128-256 KB/block part re-read (beyond-L2). Fix the
// STATE, not the occupancy: pass blocks atomicAdd their 2048-float reduced
// partial into a compact s[b,o,i] (256 KB/iter) instead of 4-8 MB part
// slabs. Consumers read 8 KB/batch. Then 512-thread pass blocks (4 waves/
// SIMD) give R9's latency hiding with R7's block count. Chain:
// k_init -> pass1 -> kB(vt1+pass2) -> kC. All math bodies R4/R7-proven;
// new primitive this round: global atomicAdd f32 (device-scope, G12).

#define N_B      32
#define IN_CAPS  1152
#define IN_LEN   32
#define OUT_CAPS 64
#define OUT_LEN  32

#define NCHUNK 16                    // n-chunks per batch -> 512 pass blocks
#define NPB    (IN_CAPS / NCHUNK)    // 72 n per block
#define PASS_WAVES 8                 // 512-thread pass blocks
#define PTHREADS 512
#define NPW    (NPB / PASS_WAVES)    // 9 n per wave
#define TSTR   36                    // padded T_lds row stride
#define SSTR   33                    // s_red row stride: bank (o+i)%32, conflict-free
#define SBYTES (OUT_CAPS * IN_LEN)   // 2048 floats per batch in s buffers

// XCD-aware decode of blockIdx.x -> (b,c): presumed round-robin XCD = d&7;
// each XCD gets 4 whole batches. Perf heuristic only, bijective (512%8==0).
#define DECODE_BC(d, b, c) \
    const int _slot = (d) >> 3; \
    const int b = ((d) & 7) * 4 + (_slot >> 4); \
    const int c = _slot & 15;

// DPP helper: butterfly step, all lanes valid.
#define DPPV(v, ctrl) \
    __int_as_float(__builtin_amdgcn_update_dpp(0, __float_as_int(v), ctrl, 0xF, 0xF, true))

__device__ __forceinline__ float wave_max(float v) {
    v = fmaxf(v, DPPV(v, 0xB1));         // quad_perm xor1
    v = fmaxf(v, DPPV(v, 0x4E));         // quad_perm xor2
    v = fmaxf(v, DPPV(v, 0x141));        // row_half_mirror
    v = fmaxf(v, DPPV(v, 0x140));        // row_mirror
    v = fmaxf(v, __shfl_xor(v, 16, 64)); // cross-row (proven path)
    v = fmaxf(v, __shfl_xor(v, 32, 64));
    return v;
}
__device__ __forceinline__ float wave_sum(float v) {
    v += DPPV(v, 0xB1);
    v += DPPV(v, 0x4E);
    v += DPPV(v, 0x141);
    v += DPPV(v, 0x140);
    v += __shfl_xor(v, 16, 64);
    v += __shfl_xor(v, 32, 64);
    return v;
}

// ---------------------------------------------------------------------------
// Pass body (R4-proven math, 512 threads): logits from pinned t[] vs
// broadcast x rows, DPP+shfl softmax (lane = o), s accumulate; flush via
// LDS atomics into s_red (stride 33), then global atomicAdd into s_glob[b].
// ---------------------------------------------------------------------------
__device__ __forceinline__ void pass_atomic(const float* __restrict__ x,
                                            const float* T_row_src, int t_stride,
                                            float* s_red,
                                            float* __restrict__ s_glob,
                                            int b, int c, int tid, int lane, int wave) {
    // zero the block accumulator
    for (int e = tid; e < OUT_CAPS * SSTR; e += PTHREADS) s_red[e] = 0.f;

    float t[IN_LEN];
    {
#pragma unroll
        for (int q = 0; q < 8; ++q) {
            const float4 v = *(const float4*)&T_row_src[lane * t_stride + q * 4];
            t[4 * q] = v.x; t[4 * q + 1] = v.y; t[4 * q + 2] = v.z; t[4 * q + 3] = v.w;
        }
    }
    asm volatile("" : "+v"(t[0]), "+v"(t[1]), "+v"(t[2]), "+v"(t[3]),
                      "+v"(t[4]), "+v"(t[5]), "+v"(t[6]), "+v"(t[7]),
                      "+v"(t[8]), "+v"(t[9]), "+v"(t[10]), "+v"(t[11]),
                      "+v"(t[12]), "+v"(t[13]), "+v"(t[14]), "+v"(t[15]));
    asm volatile("" : "+v"(t[16]), "+v"(t[17]), "+v"(t[18]), "+v"(t[19]),
                      "+v"(t[20]), "+v"(t[21]), "+v"(t[22]), "+v"(t[23]),
                      "+v"(t[24]), "+v"(t[25]), "+v"(t[26]), "+v"(t[27]),
                      "+v"(t[28]), "+v"(t[29]), "+v"(t[30]), "+v"(t[31]));

    float s[IN_LEN];
#pragma unroll
    for (int i = 0; i < IN_LEN; ++i) s[i] = 0.f;

    const float* xw = x + ((size_t)b * IN_CAPS + c * NPB + wave * NPW) * IN_LEN;

#define L4(acc, R, k) \
    acc = fmaf((R).x, t[k],     acc); acc = fmaf((R).y, t[k + 1], acc); \
    acc = fmaf((R).z, t[k + 2], acc); acc = fmaf((R).w, t[k + 3], acc);
#define S4(R, k) \
    s[k]     = fmaf(prob, (R).x, s[k]);     s[k + 1] = fmaf(prob, (R).y, s[k + 1]); \
    s[k + 2] = fmaf(prob, (R).z, s[k + 2]); s[k + 3] = fmaf(prob, (R).w, s[k + 3]);

#pragma unroll
    for (int j = 0; j < NPW; ++j) {
        const float4* xr = (const float4*)(xw + j * IN_LEN);  // wave-uniform addr
        const float4 r0 = xr[0], r1 = xr[1], r2 = xr[2], r3 = xr[3],
                     r4 = xr[4], r5 = xr[5], r6 = xr[6], r7 = xr[7];

        float l0 = 0.f, l1 = 0.f, l2 = 0.f, l3 = 0.f;
        L4(l0, r0, 0)  L4(l1, r1, 4)  L4(l2, r2, 8)  L4(l3, r3, 12)
        L4(l0, r4, 16) L4(l1, r5, 20) L4(l2, r6, 24) L4(l3, r7, 28)
        const float logit = (l0 + l1) + (l2 + l3);

        const float m = wave_max(logit);
        const float p = __expf(logit - m);
        const float S = wave_sum(p);
        const float prob = p * __builtin_amdgcn_rcpf(S);

        S4(r0, 0)  S4(r1, 4)  S4(r2, 8)  S4(r3, 12)
        S4(r4, 16) S4(r5, 20) S4(r6, 24) S4(r7, 28)
    }
#undef L4
#undef S4

    __syncthreads();                     // zeroing complete everywhere
    {
        float* row = s_red + lane * SSTR;  // bank (lane+i)%32: conflict-free
#pragma unroll
        for (int i = 0; i < IN_LEN; ++i) atomicAdd(&row[i], s[i]);
    }
    __syncthreads();                     // all wave partials accumulated

    // push block partial into compact global s[b] (coalesced, fire-and-forget)
    {
        float* sg = s_glob + (size_t)b * SBYTES;
        for (int e = tid; e < SBYTES; e += PTHREADS)
            atomicAdd(&sg[e], s_red[(e >> 5) * SSTR + (e & 31)]);
    }
}

// ---------------------------------------------------------------------------
// k_init: s0 = (1/64) sum_n x[b,n,:]; u = W@s0; squash; T = W^T@v0.
// Also zeroes s1[b], s2[b] (ws is poisoned each run). 32 blocks — the single
// cold-HBM read of x. (R0-proven core)
// ---------------------------------------------------------------------------
__global__ __launch_bounds__(256) void k_init(const float* __restrict__ x,
                                              const float* __restrict__ W,
                                              float* __restrict__ T,
                                              float* __restrict__ s1,
                                              float* __restrict__ s2) {
    const int b   = blockIdx.x;
    const int tid = threadIdx.x;
    const float* xb = x + (size_t)b * IN_CAPS * IN_LEN;

    for (int e = tid; e < SBYTES; e += 256) {
        s1[(size_t)b * SBYTES + e] = 0.f;
        s2[(size_t)b * SBYTES + e] = 0.f;
    }

    __shared__ float4 red4[32][8];
    {
        const int q = tid & 7;
        const int g = tid >> 3;
        float4 acc = make_float4(0.f, 0.f, 0.f, 0.f);
        for (int n = g; n < IN_CAPS; n += 32) {
            const float4 v = *(const float4*)(xb + n * IN_LEN + q * 4);
            acc.x += v.x; acc.y += v.y; acc.z += v.z; acc.w += v.w;
        }
        red4[g][q] = acc;
    }
    __syncthreads();
    __shared__ float s0[IN_LEN];
    if (tid < 8) {
        float4 v = make_float4(0.f, 0.f, 0.f, 0.f);
        for (int g = 0; g < 32; ++g) {
            const float4 r = red4[g][tid];
            v.x += r.x; v.y += r.y; v.z += r.z; v.w += r.w;
        }
        const float inv = 1.f / 64.f;   // uniform softmax prob at r=0
        s0[tid * 4 + 0] = v.x * inv;
        s0[tid * 4 + 1] = v.y * inv;
        s0[tid * 4 + 2] = v.z * inv;
        s0[tid * 4 + 3] = v.w * inv;
    }
    __syncthreads();

    __shared__ float u[OUT_CAPS * OUT_LEN];
    for (int e = tid; e < OUT_CAPS * OUT_LEN; e += 256) {
        const float* wrow = W + (size_t)e * IN_LEN;
        float a = 0.f;
#pragma unroll
        for (int i = 0; i < IN_LEN; ++i) a = fmaf(wrow[i], s0[i], a);
        u[e] = a;
    }
    __syncthreads();

    __shared__ float scale[OUT_CAPS];
    if (tid < OUT_CAPS) {
        float ns = 0.f;
#pragma unroll
        for (int l = 0; l < OUT_LEN; ++l) { const float v = u[tid * OUT_LEN + l]; ns = fmaf(v, v, ns); }
        scale[tid] = sqrtf(ns) / (1.f + ns);
    }
    __syncthreads();

    for (int e = tid; e < OUT_CAPS * IN_LEN; e += 256) {
        const int o = e >> 5, i = e & 31;
        float a = 0.f;
#pragma unroll
        for (int l = 0; l < OUT_LEN; ++l)
            a = fmaf(W[((size_t)o * OUT_LEN + l) * IN_LEN + i], u[o * OUT_LEN + l], a);
        T[(size_t)b * OUT_CAPS * IN_LEN + e] = a * scale[o];
    }
}

// ---------------------------------------------------------------------------
// k_pass1: routing iter 1 -> s1 (atomic). 512 blocks x 512 threads.
// ---------------------------------------------------------------------------
__global__ __launch_bounds__(PTHREADS, 4) void k_pass1(const float* __restrict__ x,
                                                       const float* __restrict__ T,
                                                       float* __restrict__ s1) {
    DECODE_BC(blockIdx.x, b, c)
    const int tid  = threadIdx.x;
    const int lane = tid & 63;
    const int wave = __builtin_amdgcn_readfirstlane(tid >> 6);

    __shared__ __align__(16) float s_red[OUT_CAPS * SSTR];   // 8.25 KB

    pass_atomic(x, T + (size_t)b * OUT_CAPS * IN_LEN, IN_LEN,
                s_red, s1, b, c, tid, lane, wave);
}

// ---------------------------------------------------------------------------
// kB: vt1 from compact s1[b] (8 KB, shared by the 16 blocks of batch b),
//     T1 = T0 + W^T v1 in LDS, then routing iter 2 -> s2 (atomic).
// ---------------------------------------------------------------------------
__global__ __launch_bounds__(PTHREADS, 4) void kB(const float* __restrict__ x,
                                                  const float* __restrict__ W,
                                                  const float* __restrict__ T,
                                                  const float* __restrict__ s1,
                                                  float* __restrict__ s2) {
    DECODE_BC(blockIdx.x, b, c)
    const int tid  = threadIdx.x;
    const int lane = tid & 63;
    const int wave = __builtin_amdgcn_readfirstlane(tid >> 6);

    __shared__ __align__(16) float T_lds[OUT_CAPS * TSTR];   // 9.2 KB
    __shared__ __align__(16) float s_red[OUT_CAPS * SSTR];   // 8.25 KB
    __shared__ __align__(16) float svt[OUT_CAPS * IN_LEN];   // 8 KB
    __shared__ __align__(16) float uu[OUT_CAPS * OUT_LEN];   // 8 KB
    __shared__ float sc[OUT_CAPS];

    // s = s1[b] (one float4 per thread)
    {
        const float4* sg4 = (const float4*)(s1 + (size_t)b * SBYTES);
        ((float4*)svt)[tid] = sg4[tid];
    }
    __syncthreads();

    for (int e = tid; e < OUT_CAPS * OUT_LEN; e += PTHREADS) {
        const int o = e >> 5;
        const float* wrow = W + (size_t)e * IN_LEN;
        const float* srow = svt + o * IN_LEN;
        float a = 0.f;
#pragma unroll
        for (int i = 0; i < IN_LEN; ++i) a = fmaf(wrow[i], srow[i], a);
        uu[e] = a;
    }
    __syncthreads();
    if (tid < OUT_CAPS) {
        float ns = 0.f;
#pragma unroll
        for (int l = 0; l < OUT_LEN; ++l) { const float v = uu[tid * OUT_LEN + l]; ns = fmaf(v, v, ns); }
        sc[tid] = sqrtf(ns) / (1.f + ns);
    }
    __syncthreads();

    // T1 = T0 + W^T @ (uu * sc)  -> LDS
    for (int e = tid; e < OUT_CAPS * IN_LEN; e += PTHREADS) {
        const int o = e >> 5, i = e & 31;
        float a = 0.f;
#pragma unroll
        for (int l = 0; l < OUT_LEN; ++l)
            a = fmaf(W[((size_t)o * OUT_LEN + l) * IN_LEN + i], uu[o * OUT_LEN + l], a);
        T_lds[o * TSTR + i] = T[(size_t)b * OUT_CAPS * IN_LEN + e] + a * sc[o];
    }
    __syncthreads();

    pass_atomic(x, T_lds, TSTR, s_red, s2, b, c, tid, lane, wave);
}

// ---------------------------------------------------------------------------
// kC: final vt from compact s2. 256 blocks = 32 b x 8 groups of 8 o.
// ---------------------------------------------------------------------------
__global__ __launch_bounds__(256) void kC(const float* __restrict__ W,
                                          const float* __restrict__ s2,
                                          float* __restrict__ out) {
    const int b   = blockIdx.x >> 3;
    const int og  = blockIdx.x & 7;
    const int tid = threadIdx.x;
    const int ol  = tid >> 5;            // 0..7 local o
    const int i   = tid & 31;            // input index / later l
    const int o   = og * 8 + ol;

    __shared__ float s_lds[8][33];
    s_lds[ol][i] = s2[(size_t)b * SBYTES + o * IN_LEN + i];
    __syncthreads();

    const float* wrow = W + ((size_t)o * OUT_LEN + i) * IN_LEN;
    float u = 0.f;
#pragma unroll
    for (int k = 0; k < IN_LEN; ++k) u = fmaf(wrow[k], s_lds[ol][k], u);

    float ns = u * u;
    ns += __shfl_xor(ns, 1, 64);
    ns += __shfl_xor(ns, 2, 64);
    ns += __shfl_xor(ns, 4, 64);
    ns += __shfl_xor(ns, 8, 64);
    ns += __shfl_xor(ns, 16, 64);
    const float scale = sqrtf(ns) / (1.f + ns);

    out[((size_t)b * OUT_CAPS + o) * OUT_LEN + i] = u * scale;
}

extern "C" void kernel_launch(void* const* d_in, const int* in_sizes, int n_in,
                              void* d_out, int out_size, void* d_ws, size_t ws_size,
                              hipStream_t stream) {
    const float* x = (const float*)d_in[0];   // [32,1152,32]
    const float* W = (const float*)d_in[1];   // [64,32,32]
    float* out = (float*)d_out;               // [32,64,32]

    float* T  = (float*)d_ws;                       // 256 KB
    float* s1 = T  + (size_t)N_B * OUT_CAPS * IN_LEN; // 256 KB (iter-1 s, atomic)
    float* s2 = s1 + (size_t)N_B * SBYTES;            // 256 KB (iter-2 s, atomic)

    k_init <<<N_B,          256,      0, stream>>>(x, W, T, s1, s2);
    k_pass1<<<N_B * NCHUNK, PTHREADS, 0, stream>>>(x, T, s1);        // iter 1
    kB     <<<N_B * NCHUNK, PTHREADS, 0, stream>>>(x, W, T, s1, s2); // vt1 + iter 2
    kC     <<<N_B * 8,      256,      0, stream>>>(W, s2, out);      // final vt
}

// Round 11
// 167.360 us; speedup vs baseline: 1.3850x; 1.2111x over previous
//
#include <hip/hip_runtime.h>
#include <math.h>

// CapsuleLinear dynamic routing, `priors` never materialized.
//   s[b,o,i]   = sum_n prob[b,o,n] * x[b,n,i]
//   out[b,o,l] = sum_i W[o,l,i] * s[b,o,i]
//   logits[b,o,n] = x[b,n,:] . T[b,o,:],  T accumulates t_r[o,i] = sum_l W[o,l,i]*v_r[o,l]
//
// R11: one-variable experiment vs the 130.0us R7 best. R10 post-mortem:
// compact-s WORKED (kB FETCH 7.9->6.0 MB) but 512-thread + launch_bounds
// (512,4) spilled the pass state (VGPR 40 -> scratch, kB 73us). So:
// R7 chain verbatim (256-thread pass blocks, (256,2), NPW=18, VGPR 68
// proven) + compact-s only:
//   - pass flush: LDS atomicAdd into stride-33 s_red, then ONE coalesced
//     global atomicAdd push into s{1,2}[b] (256 KB/iter, vs 4 MB part).
//   - kB vt1 reads s1[b] (8 KB); kC reads s2 (8 KB/batch).
//   - k_init zeroes s1/s2 (ws poisoned between runs).
// Chain: k_init -> k_pass1 -> kB(vt1+pass2) -> kC(final vt).

#define N_B      32
#define IN_CAPS  1152
#define IN_LEN   32
#define OUT_CAPS 64
#define OUT_LEN  32

#define NCHUNK 16                    // n-chunks per batch -> 512 pass blocks
#define NPB    (IN_CAPS / NCHUNK)    // 72 n per block
#define PASS_WAVES 4                 // 256-thread pass blocks (R7-proven)
#define PTHREADS 256
#define NPW    (NPB / PASS_WAVES)    // 18 n per wave
#define TSTR   36                    // padded T_lds row stride
#define SSTR   33                    // s_red row stride: bank (o+i)%32, conflict-free
#define SSZ    (OUT_CAPS * IN_LEN)   // 2048 floats per batch in s buffers

// XCD-aware decode of blockIdx.x -> (b,c): presumed round-robin XCD = d&7;
// each XCD gets 4 whole batches. Perf heuristic only, bijective (512%8==0).
#define DECODE_BC(d, b, c) \
    const int _slot = (d) >> 3; \
    const int b = ((d) & 7) * 4 + (_slot >> 4); \
    const int c = _slot & 15;

// DPP helper: butterfly step, all lanes valid.
#define DPPV(v, ctrl) \
    __int_as_float(__builtin_amdgcn_update_dpp(0, __float_as_int(v), ctrl, 0xF, 0xF, true))

__device__ __forceinline__ float wave_max(float v) {
    v = fmaxf(v, DPPV(v, 0xB1));         // quad_perm xor1
    v = fmaxf(v, DPPV(v, 0x4E));         // quad_perm xor2
    v = fmaxf(v, DPPV(v, 0x141));        // row_half_mirror
    v = fmaxf(v, DPPV(v, 0x140));        // row_mirror
    v = fmaxf(v, __shfl_xor(v, 16, 64)); // cross-row (proven path)
    v = fmaxf(v, __shfl_xor(v, 32, 64));
    return v;
}
__device__ __forceinline__ float wave_sum(float v) {
    v += DPPV(v, 0xB1);
    v += DPPV(v, 0x4E);
    v += DPPV(v, 0x141);
    v += DPPV(v, 0x140);
    v += __shfl_xor(v, 16, 64);
    v += __shfl_xor(v, 32, 64);
    return v;
}

// ---------------------------------------------------------------------------
// Pass body (R4/R7-proven math, 256 threads): logits from pinned t[] vs
// broadcast x rows, DPP+shfl softmax (lane = o), s accumulate; flush via LDS
// atomics into s_red (stride 33), then one global atomicAdd push into s[b].
// ---------------------------------------------------------------------------
__device__ __forceinline__ void pass_atomic(const float* __restrict__ x,
                                            const float* T_row_src, int t_stride,
                                            float* s_red,
                                            float* __restrict__ s_glob,
                                            int b, int c, int tid, int lane, int wave) {
    // zero the block accumulator
    for (int e = tid; e < OUT_CAPS * SSTR; e += PTHREADS) s_red[e] = 0.f;

    float t[IN_LEN];
    {
#pragma unroll
        for (int q = 0; q < 8; ++q) {
            const float4 v = *(const float4*)&T_row_src[lane * t_stride + q * 4];
            t[4 * q] = v.x; t[4 * q + 1] = v.y; t[4 * q + 2] = v.z; t[4 * q + 3] = v.w;
        }
    }
    asm volatile("" : "+v"(t[0]), "+v"(t[1]), "+v"(t[2]), "+v"(t[3]),
                      "+v"(t[4]), "+v"(t[5]), "+v"(t[6]), "+v"(t[7]),
                      "+v"(t[8]), "+v"(t[9]), "+v"(t[10]), "+v"(t[11]),
                      "+v"(t[12]), "+v"(t[13]), "+v"(t[14]), "+v"(t[15]));
    asm volatile("" : "+v"(t[16]), "+v"(t[17]), "+v"(t[18]), "+v"(t[19]),
                      "+v"(t[20]), "+v"(t[21]), "+v"(t[22]), "+v"(t[23]),
                      "+v"(t[24]), "+v"(t[25]), "+v"(t[26]), "+v"(t[27]),
                      "+v"(t[28]), "+v"(t[29]), "+v"(t[30]), "+v"(t[31]));

    float s[IN_LEN];
#pragma unroll
    for (int i = 0; i < IN_LEN; ++i) s[i] = 0.f;

    const float* xw = x + ((size_t)b * IN_CAPS + c * NPB + wave * NPW) * IN_LEN;

#define L4(acc, R, k) \
    acc = fmaf((R).x, t[k],     acc); acc = fmaf((R).y, t[k + 1], acc); \
    acc = fmaf((R).z, t[k + 2], acc); acc = fmaf((R).w, t[k + 3], acc);
#define S4(R, k) \
    s[k]     = fmaf(prob, (R).x, s[k]);     s[k + 1] = fmaf(prob, (R).y, s[k + 1]); \
    s[k + 2] = fmaf(prob, (R).z, s[k + 2]); s[k + 3] = fmaf(prob, (R).w, s[k + 3]);

#pragma unroll
    for (int j = 0; j < NPW; ++j) {
        const float4* xr = (const float4*)(xw + j * IN_LEN);  // wave-uniform addr
        const float4 r0 = xr[0], r1 = xr[1], r2 = xr[2], r3 = xr[3],
                     r4 = xr[4], r5 = xr[5], r6 = xr[6], r7 = xr[7];

        float l0 = 0.f, l1 = 0.f, l2 = 0.f, l3 = 0.f;
        L4(l0, r0, 0)  L4(l1, r1, 4)  L4(l2, r2, 8)  L4(l3, r3, 12)
        L4(l0, r4, 16) L4(l1, r5, 20) L4(l2, r6, 24) L4(l3, r7, 28)
        const float logit = (l0 + l1) + (l2 + l3);

        const float m = wave_max(logit);
        const float p = __expf(logit - m);
        const float S = wave_sum(p);
        const float prob = p * __builtin_amdgcn_rcpf(S);

        S4(r0, 0)  S4(r1, 4)  S4(r2, 8)  S4(r3, 12)
        S4(r4, 16) S4(r5, 20) S4(r6, 24) S4(r7, 28)
    }
#undef L4
#undef S4

    __syncthreads();                     // zeroing complete everywhere
    {
        float* row = s_red + lane * SSTR;  // bank (lane+i)%32: conflict-free
#pragma unroll
        for (int i = 0; i < IN_LEN; ++i) atomicAdd(&row[i], s[i]);
    }
    __syncthreads();                     // all wave partials accumulated

    // push block partial into compact global s[b] (coalesced, fire-and-forget)
    {
        float* sg = s_glob + (size_t)b * SSZ;
        for (int e = tid; e < SSZ; e += PTHREADS)
            atomicAdd(&sg[e], s_red[(e >> 5) * SSTR + (e & 31)]);
    }
}

// ---------------------------------------------------------------------------
// k_init: s0 = (1/64) sum_n x[b,n,:]; u = W@s0; squash; T = W^T@v0.
// Also zeroes s1[b], s2[b]. 32 blocks — the single cold-HBM read of x.
// (R0-proven core + R10-proven zeroing)
// ---------------------------------------------------------------------------
__global__ __launch_bounds__(256) void k_init(const float* __restrict__ x,
                                              const float* __restrict__ W,
                                              float* __restrict__ T,
                                              float* __restrict__ s1,
                                              float* __restrict__ s2) {
    const int b   = blockIdx.x;
    const int tid = threadIdx.x;
    const float* xb = x + (size_t)b * IN_CAPS * IN_LEN;

    for (int e = tid; e < SSZ; e += 256) {
        s1[(size_t)b * SSZ + e] = 0.f;
        s2[(size_t)b * SSZ + e] = 0.f;
    }

    __shared__ float4 red4[32][8];
    {
        const int q = tid & 7;
        const int g = tid >> 3;
        float4 acc = make_float4(0.f, 0.f, 0.f, 0.f);
        for (int n = g; n < IN_CAPS; n += 32) {
            const float4 v = *(const float4*)(xb + n * IN_LEN + q * 4);
            acc.x += v.x; acc.y += v.y; acc.z += v.z; acc.w += v.w;
        }
        red4[g][q] = acc;
    }
    __syncthreads();
    __shared__ float s0[IN_LEN];
    if (tid < 8) {
        float4 v = make_float4(0.f, 0.f, 0.f, 0.f);
        for (int g = 0; g < 32; ++g) {
            const float4 r = red4[g][tid];
            v.x += r.x; v.y += r.y; v.z += r.z; v.w += r.w;
        }
        const float inv = 1.f / 64.f;   // uniform softmax prob at r=0
        s0[tid * 4 + 0] = v.x * inv;
        s0[tid * 4 + 1] = v.y * inv;
        s0[tid * 4 + 2] = v.z * inv;
        s0[tid * 4 + 3] = v.w * inv;
    }
    __syncthreads();

    __shared__ float u[OUT_CAPS * OUT_LEN];
    for (int e = tid; e < OUT_CAPS * OUT_LEN; e += 256) {
        const float* wrow = W + (size_t)e * IN_LEN;
        float a = 0.f;
#pragma unroll
        for (int i = 0; i < IN_LEN; ++i) a = fmaf(wrow[i], s0[i], a);
        u[e] = a;
    }
    __syncthreads();

    __shared__ float scale[OUT_CAPS];
    if (tid < OUT_CAPS) {
        float ns = 0.f;
#pragma unroll
        for (int l = 0; l < OUT_LEN; ++l) { const float v = u[tid * OUT_LEN + l]; ns = fmaf(v, v, ns); }
        scale[tid] = sqrtf(ns) / (1.f + ns);
    }
    __syncthreads();

    for (int e = tid; e < OUT_CAPS * IN_LEN; e += 256) {
        const int o = e >> 5, i = e & 31;
        float a = 0.f;
#pragma unroll
        for (int l = 0; l < OUT_LEN; ++l)
            a = fmaf(W[((size_t)o * OUT_LEN + l) * IN_LEN + i], u[o * OUT_LEN + l], a);
        T[(size_t)b * OUT_CAPS * IN_LEN + e] = a * scale[o];
    }
}

// ---------------------------------------------------------------------------
// k_pass1: routing iter 1 -> s1 (atomic). 512 blocks x 256 threads, (256,2).
// ---------------------------------------------------------------------------
__global__ __launch_bounds__(PTHREADS, 2) void k_pass1(const float* __restrict__ x,
                                                       const float* __restrict__ T,
                                                       float* __restrict__ s1) {
    DECODE_BC(blockIdx.x, b, c)
    const int tid  = threadIdx.x;
    const int lane = tid & 63;
    const int wave = __builtin_amdgcn_readfirstlane(tid >> 6);

    __shared__ __align__(16) float s_red[OUT_CAPS * SSTR];   // 8.25 KB

    pass_atomic(x, T + (size_t)b * OUT_CAPS * IN_LEN, IN_LEN,
                s_red, s1, b, c, tid, lane, wave);
}

// ---------------------------------------------------------------------------
// kB: vt1 from compact s1[b] (8 KB), T1 = T0 + W^T v1 in LDS, then routing
//     iter 2 -> s2 (atomic). (256,2) like R7 — VGPR headroom preserved.
// ---------------------------------------------------------------------------
__global__ __launch_bounds__(PTHREADS, 2) void kB(const float* __restrict__ x,
                                                  const float* __restrict__ W,
                                                  const float* __restrict__ T,
                                                  const float* __restrict__ s1,
                                                  float* __restrict__ s2) {
    DECODE_BC(blockIdx.x, b, c)
    const int tid  = threadIdx.x;
    const int lane = tid & 63;
    const int wave = __builtin_amdgcn_readfirstlane(tid >> 6);

    __shared__ __align__(16) float T_lds[OUT_CAPS * TSTR];   // 9.2 KB
    __shared__ __align__(16) float s_red[OUT_CAPS * SSTR];   // 8.25 KB
    __shared__ __align__(16) float svt[OUT_CAPS * IN_LEN];   // 8 KB
    __shared__ __align__(16) float uu[OUT_CAPS * OUT_LEN];   // 8 KB
    __shared__ float sc[OUT_CAPS];

    // s = s1[b]: 512 float4 loads by 256 threads
    {
        const float4* sg4 = (const float4*)(s1 + (size_t)b * SSZ);
        float4* d4 = (float4*)svt;
        d4[tid] = sg4[tid];
        d4[tid + 256] = sg4[tid + 256];
    }
    __syncthreads();

    for (int e = tid; e < OUT_CAPS * OUT_LEN; e += PTHREADS) {
        const int o = e >> 5;
        const float* wrow = W + (size_t)e * IN_LEN;
        const float* srow = svt + o * IN_LEN;
        float a = 0.f;
#pragma unroll
        for (int i = 0; i < IN_LEN; ++i) a = fmaf(wrow[i], srow[i], a);
        uu[e] = a;
    }
    __syncthreads();
    if (tid < OUT_CAPS) {
        float ns = 0.f;
#pragma unroll
        for (int l = 0; l < OUT_LEN; ++l) { const float v = uu[tid * OUT_LEN + l]; ns = fmaf(v, v, ns); }
        sc[tid] = sqrtf(ns) / (1.f + ns);
    }
    __syncthreads();

    // T1 = T0 + W^T @ (uu * sc)  -> LDS
    for (int e = tid; e < OUT_CAPS * IN_LEN; e += PTHREADS) {
        const int o = e >> 5, i = e & 31;
        float a = 0.f;
#pragma unroll
        for (int l = 0; l < OUT_LEN; ++l)
            a = fmaf(W[((size_t)o * OUT_LEN + l) * IN_LEN + i], uu[o * OUT_LEN + l], a);
        T_lds[o * TSTR + i] = T[(size_t)b * OUT_CAPS * IN_LEN + e] + a * sc[o];
    }
    __syncthreads();

    pass_atomic(x, T_lds, TSTR, s_red, s2, b, c, tid, lane, wave);
}

// ---------------------------------------------------------------------------
// kC: final vt from compact s2. 256 blocks = 32 b x 8 groups of 8 o.
// (R6-proven pattern)
// ---------------------------------------------------------------------------
__global__ __launch_bounds__(256) void kC(const float* __restrict__ W,
                                          const float* __restrict__ s2,
                                          float* __restrict__ out) {
    const int b   = blockIdx.x >> 3;
    const int og  = blockIdx.x & 7;
    const int tid = threadIdx.x;
    const int ol  = tid >> 5;            // 0..7 local o
    const int i   = tid & 31;            // input index / later l
    const int o   = og * 8 + ol;

    __shared__ float s_lds[8][33];
    s_lds[ol][i] = s2[(size_t)b * SSZ + o * IN_LEN + i];
    __syncthreads();

    const float* wrow = W + ((size_t)o * OUT_LEN + i) * IN_LEN;
    float u = 0.f;
#pragma unroll
    for (int k = 0; k < IN_LEN; ++k) u = fmaf(wrow[k], s_lds[ol][k], u);

    float ns = u * u;
    ns += __shfl_xor(ns, 1, 64);
    ns += __shfl_xor(ns, 2, 64);
    ns += __shfl_xor(ns, 4, 64);
    ns += __shfl_xor(ns, 8, 64);
    ns += __shfl_xor(ns, 16, 64);
    const float scale = sqrtf(ns) / (1.f + ns);

    out[((size_t)b * OUT_CAPS + o) * OUT_LEN + i] = u * scale;
}

extern "C" void kernel_launch(void* const* d_in, const int* in_sizes, int n_in,
                              void* d_out, int out_size, void* d_ws, size_t ws_size,
                              hipStream_t stream) {
    const float* x = (const float*)d_in[0];   // [32,1152,32]
    const float* W = (const float*)d_in[1];   // [64,32,32]
    float* out = (float*)d_out;               // [32,64,32]

    float* T  = (float*)d_ws;                         // 256 KB
    float* s1 = T  + (size_t)N_B * OUT_CAPS * IN_LEN; // 256 KB (iter-1 s, atomic)
    float* s2 = s1 + (size_t)N_B * SSZ;               // 256 KB (iter-2 s, atomic)

    k_init <<<N_B,          256,      0, stream>>>(x, W, T, s1, s2);
    k_pass1<<<N_B * NCHUNK, PTHREADS, 0, stream>>>(x, T, s1);        // iter 1
    kB     <<<N_B * NCHUNK, PTHREADS, 0, stream>>>(x, W, T, s1, s2); // vt1 + iter 2
    kC     <<<N_B * 8,      256,      0, stream>>>(W, s2, out);      // final vt
}

// Round 12
// 129.999 us; speedup vs baseline: 1.7830x; 1.2874x over previous
//
#include <hip/hip_runtime.h>
#include <math.h>

// CapsuleLinear dynamic routing, `priors` never materialized.
//   s[b,o,i]   = sum_n prob[b,o,n] * x[b,n,i]
//   out[b,o,l] = sum_i W[o,l,i] * s[b,o,i]
//   logits[b,o,n] = x[b,n,:] . T[b,o,:],  T accumulates t_r[o,i] = sum_l W[o,l,i]*v_r[o,l]
//
// R12: R7 chain (130.0us best) with ONE pass-body change. R11 post-mortem +
// R7 counter arithmetic: VGPR 68 < the ~100 the source wants => t[] is NOT
// register-resident despite the asm pin; the compiler re-reads it per use.
// In kB those re-reads hit T_lds stride 36 -> bank (4*lane+i)%32 = 8-way
// conflict on ~576 reads/row-loop (SQ_LDS_BANK_CONFLICT 180K). In pass1 they
// go to GLOBAL (R1 failure mode, L2-softened). Fix: embrace the re-read —
// t lives in stride-33 LDS (bank (lane+i)%32: 64 lanes/32 banks = 2-way =
// free), no t[] array, no pins. s[32] stays in regs. Everything else R7
// verbatim: part slabs, padded-LDS flush, kB vt-reduce, kC o-split, k_init.

#define N_B      32
#define IN_CAPS  1152
#define IN_LEN   32
#define OUT_CAPS 64
#define OUT_LEN  32

#define NCHUNK 16                    // n-chunks per batch -> 512 pass blocks
#define NPB    (IN_CAPS / NCHUNK)    // 72 n per block
#define PASS_WAVES 4                 // 256-thread pass blocks
#define NPW    (NPB / PASS_WAVES)    // 18 n per wave
#define TSTR   33                    // t_lds row stride: bank (o+i)%32, conflict-free
#define FSTR   36                    // flush buf row stride (16B-aligned, R7-proven)

// XCD-aware decode of blockIdx.x -> (b,c): presumed round-robin XCD = d&7;
// each XCD gets 4 whole batches. Perf heuristic only, bijective (512%8==0).
#define DECODE_BC(d, b, c) \
    const int _slot = (d) >> 3; \
    const int b = ((d) & 7) * 4 + (_slot >> 4); \
    const int c = _slot & 15;

// DPP helper: butterfly step, all lanes valid.
#define DPPV(v, ctrl) \
    __int_as_float(__builtin_amdgcn_update_dpp(0, __float_as_int(v), ctrl, 0xF, 0xF, true))

__device__ __forceinline__ float wave_max(float v) {
    v = fmaxf(v, DPPV(v, 0xB1));         // quad_perm xor1
    v = fmaxf(v, DPPV(v, 0x4E));         // quad_perm xor2
    v = fmaxf(v, DPPV(v, 0x141));        // row_half_mirror
    v = fmaxf(v, DPPV(v, 0x140));        // row_mirror
    v = fmaxf(v, __shfl_xor(v, 16, 64)); // cross-row (proven path)
    v = fmaxf(v, __shfl_xor(v, 32, 64));
    return v;
}
__device__ __forceinline__ float wave_sum(float v) {
    v += DPPV(v, 0xB1);
    v += DPPV(v, 0x4E);
    v += DPPV(v, 0x141);
    v += DPPV(v, 0x140);
    v += __shfl_xor(v, 16, 64);
    v += __shfl_xor(v, 32, 64);
    return v;
}

// ---------------------------------------------------------------------------
// Pass body v2: logits read t from conflict-free LDS (stride 33) per use —
// the compiler may hoist into regs (it has budget) or re-read (free either
// way). x rows via broadcast VMEM (R7-proven). DPP+shfl softmax (lane = o).
// Flush: R7-proven padded-LDS block reduce -> part[b,c] slab.
// ---------------------------------------------------------------------------
__device__ __forceinline__ void pass_v2(const float* __restrict__ x,
                                        const float* t_lds,   // [64*TSTR], filled
                                        float* buf,           // [4*64*FSTR]
                                        float* __restrict__ part_out,
                                        int b, int c, int tid, int lane, int wave) {
    float s[IN_LEN];
#pragma unroll
    for (int i = 0; i < IN_LEN; ++i) s[i] = 0.f;

    const float* xw = x + ((size_t)b * IN_CAPS + c * NPB + wave * NPW) * IN_LEN;
    const float* tr = t_lds + lane * TSTR;

#define L4(acc, R, k) \
    acc = fmaf((R).x, tr[k],     acc); acc = fmaf((R).y, tr[k + 1], acc); \
    acc = fmaf((R).z, tr[k + 2], acc); acc = fmaf((R).w, tr[k + 3], acc);
#define S4(R, k) \
    s[k]     = fmaf(prob, (R).x, s[k]);     s[k + 1] = fmaf(prob, (R).y, s[k + 1]); \
    s[k + 2] = fmaf(prob, (R).z, s[k + 2]); s[k + 3] = fmaf(prob, (R).w, s[k + 3]);

#pragma unroll
    for (int j = 0; j < NPW; ++j) {
        const float4* xr = (const float4*)(xw + j * IN_LEN);  // wave-uniform addr
        const float4 r0 = xr[0], r1 = xr[1], r2 = xr[2], r3 = xr[3],
                     r4 = xr[4], r5 = xr[5], r6 = xr[6], r7 = xr[7];

        float l0 = 0.f, l1 = 0.f, l2 = 0.f, l3 = 0.f;
        L4(l0, r0, 0)  L4(l1, r1, 4)  L4(l2, r2, 8)  L4(l3, r3, 12)
        L4(l0, r4, 16) L4(l1, r5, 20) L4(l2, r6, 24) L4(l3, r7, 28)
        const float logit = (l0 + l1) + (l2 + l3);

        const float m = wave_max(logit);
        const float p = __expf(logit - m);
        const float S = wave_sum(p);
        const float prob = p * __builtin_amdgcn_rcpf(S);

        S4(r0, 0)  S4(r1, 4)  S4(r2, 8)  S4(r3, 12)
        S4(r4, 16) S4(r5, 20) S4(r6, 24) S4(r7, 28)
    }
#undef L4
#undef S4

    // flush: per-wave rows into padded buf, block-reduce, write part[b,c]
    {
        float4* dst = (float4*)&buf[(wave * OUT_CAPS + lane) * FSTR];
#pragma unroll
        for (int q = 0; q < 8; ++q)
            dst[q] = make_float4(s[4 * q], s[4 * q + 1], s[4 * q + 2], s[4 * q + 3]);
    }
    __syncthreads();
    {
        float4* pb4 = (float4*)(part_out + ((size_t)b * NCHUNK + c) * OUT_CAPS * IN_LEN);
        for (int e = tid; e < OUT_CAPS * IN_LEN / 4; e += 256) {
            const int o = e >> 3, q4 = (e & 7) * 4;
            const float4 a0 = *(const float4*)&buf[(0 * OUT_CAPS + o) * FSTR + q4];
            const float4 a1 = *(const float4*)&buf[(1 * OUT_CAPS + o) * FSTR + q4];
            const float4 a2 = *(const float4*)&buf[(2 * OUT_CAPS + o) * FSTR + q4];
            const float4 a3 = *(const float4*)&buf[(3 * OUT_CAPS + o) * FSTR + q4];
            pb4[e] = make_float4(a0.x + a1.x + a2.x + a3.x,
                                 a0.y + a1.y + a2.y + a3.y,
                                 a0.z + a1.z + a2.z + a3.z,
                                 a0.w + a1.w + a2.w + a3.w);
        }
    }
}

// ---------------------------------------------------------------------------
// k_init: s0 = (1/64) sum_n x[b,n,:]; u = W@s0; squash; T = W^T@v0.
// 32 blocks — the single cold-HBM read of x. (R0-proven)
// ---------------------------------------------------------------------------
__global__ __launch_bounds__(256) void k_init(const float* __restrict__ x,
                                              const float* __restrict__ W,
                                              float* __restrict__ T) {
    const int b   = blockIdx.x;
    const int tid = threadIdx.x;
    const float* xb = x + (size_t)b * IN_CAPS * IN_LEN;

    __shared__ float4 red4[32][8];
    {
        const int q = tid & 7;
        const int g = tid >> 3;
        float4 acc = make_float4(0.f, 0.f, 0.f, 0.f);
        for (int n = g; n < IN_CAPS; n += 32) {
            const float4 v = *(const float4*)(xb + n * IN_LEN + q * 4);
            acc.x += v.x; acc.y += v.y; acc.z += v.z; acc.w += v.w;
        }
        red4[g][q] = acc;
    }
    __syncthreads();
    __shared__ float s0[IN_LEN];
    if (tid < 8) {
        float4 v = make_float4(0.f, 0.f, 0.f, 0.f);
        for (int g = 0; g < 32; ++g) {
            const float4 r = red4[g][tid];
            v.x += r.x; v.y += r.y; v.z += r.z; v.w += r.w;
        }
        const float inv = 1.f / 64.f;   // uniform softmax prob at r=0
        s0[tid * 4 + 0] = v.x * inv;
        s0[tid * 4 + 1] = v.y * inv;
        s0[tid * 4 + 2] = v.z * inv;
        s0[tid * 4 + 3] = v.w * inv;
    }
    __syncthreads();

    __shared__ float u[OUT_CAPS * OUT_LEN];
    for (int e = tid; e < OUT_CAPS * OUT_LEN; e += 256) {
        const float* wrow = W + (size_t)e * IN_LEN;
        float a = 0.f;
#pragma unroll
        for (int i = 0; i < IN_LEN; ++i) a = fmaf(wrow[i], s0[i], a);
        u[e] = a;
    }
    __syncthreads();

    __shared__ float scale[OUT_CAPS];
    if (tid < OUT_CAPS) {
        float ns = 0.f;
#pragma unroll
        for (int l = 0; l < OUT_LEN; ++l) { const float v = u[tid * OUT_LEN + l]; ns = fmaf(v, v, ns); }
        scale[tid] = sqrtf(ns) / (1.f + ns);
    }
    __syncthreads();

    for (int e = tid; e < OUT_CAPS * IN_LEN; e += 256) {
        const int o = e >> 5, i = e & 31;
        float a = 0.f;
#pragma unroll
        for (int l = 0; l < OUT_LEN; ++l)
            a = fmaf(W[((size_t)o * OUT_LEN + l) * IN_LEN + i], u[o * OUT_LEN + l], a);
        T[(size_t)b * OUT_CAPS * IN_LEN + e] = a * scale[o];
    }
}

// ---------------------------------------------------------------------------
// k_pass1: stage T[b] -> stride-33 LDS, then routing iter 1 -> part.
// ---------------------------------------------------------------------------
__global__ __launch_bounds__(256, 2) void k_pass1(const float* __restrict__ x,
                                                  const float* __restrict__ T,
                                                  float* __restrict__ part) {
    DECODE_BC(blockIdx.x, b, c)
    const int tid  = threadIdx.x;
    const int lane = tid & 63;
    const int wave = __builtin_amdgcn_readfirstlane(tid >> 6);

    __shared__ float t_lds[OUT_CAPS * TSTR];                         // 8.25 KB
    __shared__ __align__(16) float buf[PASS_WAVES * OUT_CAPS * FSTR]; // 36 KB

    {
        const float* Tb = T + (size_t)b * OUT_CAPS * IN_LEN;
        for (int e = tid; e < OUT_CAPS * IN_LEN; e += 256)
            t_lds[(e >> 5) * TSTR + (e & 31)] = Tb[e];   // coalesced read, cf write
    }
    __syncthreads();

    pass_v2(x, t_lds, buf, part, b, c, tid, lane, wave);
}

// ---------------------------------------------------------------------------
// kB: redundant vt-reduce (16 slabs of part -> s -> u -> squash;
//     T1 = T0 + W^T v1 into stride-33 LDS), then routing iter 2 -> part2.
// ---------------------------------------------------------------------------
__global__ __launch_bounds__(256, 2) void kB(const float* __restrict__ x,
                                             const float* __restrict__ W,
                                             const float* __restrict__ T,
                                             const float* __restrict__ part,
                                             float* __restrict__ part2) {
    DECODE_BC(blockIdx.x, b, c)
    const int tid  = threadIdx.x;
    const int lane = tid & 63;
    const int wave = __builtin_amdgcn_readfirstlane(tid >> 6);

    __shared__ float t_lds[OUT_CAPS * TSTR];                          // 8.25 KB
    __shared__ __align__(16) float buf[PASS_WAVES * OUT_CAPS * FSTR]; // 36 KB

    float* s_lds = buf;          // 2048 floats (aliased pre-pass, R7-proven)
    float* uu    = buf + 2048;   // 2048
    float* sc    = buf + 4096;   // 64

    // ---- redundant vt-reduce (R7-proven) ----
    {
        const float4* pb4 = (const float4*)(part + (size_t)b * NCHUNK * OUT_CAPS * IN_LEN);
        for (int e = tid; e < OUT_CAPS * IN_LEN / 4; e += 256) {
            float4 acc = make_float4(0.f, 0.f, 0.f, 0.f);
#pragma unroll
            for (int cc = 0; cc < NCHUNK; ++cc) {
                const float4 v = pb4[cc * (OUT_CAPS * IN_LEN / 4) + e];
                acc.x += v.x; acc.y += v.y; acc.z += v.z; acc.w += v.w;
            }
            ((float4*)s_lds)[e] = acc;
        }
    }
    __syncthreads();
    for (int e = tid; e < OUT_CAPS * OUT_LEN; e += 256) {
        const int o = e >> 5;
        const float* wrow = W + (size_t)e * IN_LEN;
        const float* srow = s_lds + o * IN_LEN;
        float a = 0.f;
#pragma unroll
        for (int i = 0; i < IN_LEN; ++i) a = fmaf(wrow[i], srow[i], a);
        uu[e] = a;
    }
    __syncthreads();
    if (tid < OUT_CAPS) {
        float ns = 0.f;
#pragma unroll
        for (int l = 0; l < OUT_LEN; ++l) { const float v = uu[tid * OUT_LEN + l]; ns = fmaf(v, v, ns); }
        sc[tid] = sqrtf(ns) / (1.f + ns);
    }
    __syncthreads();

    // T1 = T0 + W^T @ (uu * sc)  -> stride-33 LDS (conflict-free writes)
    for (int e = tid; e < OUT_CAPS * IN_LEN; e += 256) {
        const int o = e >> 5, i = e & 31;
        float a = 0.f;
#pragma unroll
        for (int l = 0; l < OUT_LEN; ++l)
            a = fmaf(W[((size_t)o * OUT_LEN + l) * IN_LEN + i], uu[o * OUT_LEN + l], a);
        t_lds[o * TSTR + i] = T[(size_t)b * OUT_CAPS * IN_LEN + e] + a * sc[o];
    }
    __syncthreads();

    pass_v2(x, t_lds, buf, part2, b, c, tid, lane, wave);
}

// ---------------------------------------------------------------------------
// kC: final vt, split by o-group. 256 blocks = 32 b x 8 groups of 8 o.
// (R6/R7-proven; reads part2)
// ---------------------------------------------------------------------------
__global__ __launch_bounds__(256) void kC(const float* __restrict__ W,
                                          const float* __restrict__ part2,
                                          float* __restrict__ out) {
    const int b   = blockIdx.x >> 3;
    const int og  = blockIdx.x & 7;
    const int tid = threadIdx.x;
    const int ol  = tid >> 5;            // 0..7 local o
    const int i   = tid & 31;            // input index / later l
    const int o   = og * 8 + ol;

    float a = 0.f;
    const float* pb = part2 + (size_t)b * NCHUNK * OUT_CAPS * IN_LEN + o * IN_LEN + i;
#pragma unroll
    for (int cc = 0; cc < NCHUNK; ++cc) a += pb[cc * OUT_CAPS * IN_LEN];

    __shared__ float s_lds[8][33];
    s_lds[ol][i] = a;
    __syncthreads();

    const float* wrow = W + ((size_t)o * OUT_LEN + i) * IN_LEN;
    float u = 0.f;
#pragma unroll
    for (int k = 0; k < IN_LEN; ++k) u = fmaf(wrow[k], s_lds[ol][k], u);

    float ns = u * u;
    ns += __shfl_xor(ns, 1, 64);
    ns += __shfl_xor(ns, 2, 64);
    ns += __shfl_xor(ns, 4, 64);
    ns += __shfl_xor(ns, 8, 64);
    ns += __shfl_xor(ns, 16, 64);
    const float scale = sqrtf(ns) / (1.f + ns);

    out[((size_t)b * OUT_CAPS + o) * OUT_LEN + i] = u * scale;
}

extern "C" void kernel_launch(void* const* d_in, const int* in_sizes, int n_in,
                              void* d_out, int out_size, void* d_ws, size_t ws_size,
                              hipStream_t stream) {
    const float* x = (const float*)d_in[0];   // [32,1152,32]
    const float* W = (const float*)d_in[1];   // [64,32,32]
    float* out = (float*)d_out;               // [32,64,32]

    float* T     = (float*)d_ws;                          // 256 KB
    float* part  = T + (size_t)N_B * OUT_CAPS * IN_LEN;   // 4 MB (iter-1 partials)
    float* part2 = part + (size_t)N_B * NCHUNK * OUT_CAPS * IN_LEN; // 4 MB (iter-2)

    k_init <<<N_B,          256, 0, stream>>>(x, W, T);
    k_pass1<<<N_B * NCHUNK, 256, 0, stream>>>(x, T, part);           // iter 1
    kB     <<<N_B * NCHUNK, 256, 0, stream>>>(x, W, T, part, part2); // vt1 + iter 2
    kC     <<<N_B * 8,      256, 0, stream>>>(W, part2, out);        // final vt
}

// Round 13
// 120.611 us; speedup vs baseline: 1.9218x; 1.0778x over previous
//
#include <hip/hip_runtime.h>
#include <math.h>

// CapsuleLinear dynamic routing, `priors` never materialized.
//   s[b,o,i]   = sum_n prob[b,o,n] * x[b,n,i]
//   out[b,o,l] = sum_i W[o,l,i] * s[b,o,i]
//   logits[b,o,n] = x[b,n,:] . T[b,o,:],  T accumulates t_r[o,i] = sum_l W[o,l,i]*v_r[o,l]
//
// R13: R12 base (130.0us, ties best) + three targeted edits, no new
// primitives:
//   1. XCD-align k_init and kC with the pass DECODE (batch b <-> XCD b/4):
//      k_init block d -> batch (d&7)*4+(d>>3); kC b=(d&7)*4+((d>>3)&3),
//      og=d>>5. x/part slabs become L2-local for every consumer (previously
//      k_init warmed XCD b%8 while passes ran on XCD b/4 -> L3 misses).
//   2. kB vt-reduce wave-split: wave w sums slabs {w,w+4,w+8,w+12} (chain
//      depth 32 -> 8x4, 4x memory parallelism), partials in buf, in-place
//      combine.
//   3. k_init at 512 threads (R8-proven phase-0 shape) for the cold x read.
// Chain: k_init -> k_pass1 -> kB(vt1+pass2) -> kC(final vt).

#define N_B      32
#define IN_CAPS  1152
#define IN_LEN   32
#define OUT_CAPS 64
#define OUT_LEN  32

#define NCHUNK 16                    // n-chunks per batch -> 512 pass blocks
#define NPB    (IN_CAPS / NCHUNK)    // 72 n per block
#define PASS_WAVES 4                 // 256-thread pass blocks
#define NPW    (NPB / PASS_WAVES)    // 18 n per wave
#define TSTR   33                    // t_lds row stride: bank (o+i)%32, conflict-free
#define FSTR   36                    // flush buf row stride (16B-aligned, R7-proven)

// XCD-aware decode of blockIdx.x -> (b,c): presumed round-robin XCD = d&7;
// each XCD gets 4 whole batches. Perf heuristic only, bijective (512%8==0).
#define DECODE_BC(d, b, c) \
    const int _slot = (d) >> 3; \
    const int b = ((d) & 7) * 4 + (_slot >> 4); \
    const int c = _slot & 15;

// DPP helper: butterfly step, all lanes valid.
#define DPPV(v, ctrl) \
    __int_as_float(__builtin_amdgcn_update_dpp(0, __float_as_int(v), ctrl, 0xF, 0xF, true))

__device__ __forceinline__ float wave_max(float v) {
    v = fmaxf(v, DPPV(v, 0xB1));         // quad_perm xor1
    v = fmaxf(v, DPPV(v, 0x4E));         // quad_perm xor2
    v = fmaxf(v, DPPV(v, 0x141));        // row_half_mirror
    v = fmaxf(v, DPPV(v, 0x140));        // row_mirror
    v = fmaxf(v, __shfl_xor(v, 16, 64)); // cross-row (proven path)
    v = fmaxf(v, __shfl_xor(v, 32, 64));
    return v;
}
__device__ __forceinline__ float wave_sum(float v) {
    v += DPPV(v, 0xB1);
    v += DPPV(v, 0x4E);
    v += DPPV(v, 0x141);
    v += DPPV(v, 0x140);
    v += __shfl_xor(v, 16, 64);
    v += __shfl_xor(v, 32, 64);
    return v;
}

// ---------------------------------------------------------------------------
// Pass body (R12-proven): logits read t from conflict-free stride-33 LDS,
// x rows via broadcast VMEM, DPP+shfl softmax (lane = o), s[32] in regs.
// Flush: padded-LDS block reduce -> part[b,c] slab.
// ---------------------------------------------------------------------------
__device__ __forceinline__ void pass_v2(const float* __restrict__ x,
                                        const float* t_lds,   // [64*TSTR], filled
                                        float* buf,           // [4*64*FSTR]
                                        float* __restrict__ part_out,
                                        int b, int c, int tid, int lane, int wave) {
    float s[IN_LEN];
#pragma unroll
    for (int i = 0; i < IN_LEN; ++i) s[i] = 0.f;

    const float* xw = x + ((size_t)b * IN_CAPS + c * NPB + wave * NPW) * IN_LEN;
    const float* tr = t_lds + lane * TSTR;

#define L4(acc, R, k) \
    acc = fmaf((R).x, tr[k],     acc); acc = fmaf((R).y, tr[k + 1], acc); \
    acc = fmaf((R).z, tr[k + 2], acc); acc = fmaf((R).w, tr[k + 3], acc);
#define S4(R, k) \
    s[k]     = fmaf(prob, (R).x, s[k]);     s[k + 1] = fmaf(prob, (R).y, s[k + 1]); \
    s[k + 2] = fmaf(prob, (R).z, s[k + 2]); s[k + 3] = fmaf(prob, (R).w, s[k + 3]);

#pragma unroll
    for (int j = 0; j < NPW; ++j) {
        const float4* xr = (const float4*)(xw + j * IN_LEN);  // wave-uniform addr
        const float4 r0 = xr[0], r1 = xr[1], r2 = xr[2], r3 = xr[3],
                     r4 = xr[4], r5 = xr[5], r6 = xr[6], r7 = xr[7];

        float l0 = 0.f, l1 = 0.f, l2 = 0.f, l3 = 0.f;
        L4(l0, r0, 0)  L4(l1, r1, 4)  L4(l2, r2, 8)  L4(l3, r3, 12)
        L4(l0, r4, 16) L4(l1, r5, 20) L4(l2, r6, 24) L4(l3, r7, 28)
        const float logit = (l0 + l1) + (l2 + l3);

        const float m = wave_max(logit);
        const float p = __expf(logit - m);
        const float S = wave_sum(p);
        const float prob = p * __builtin_amdgcn_rcpf(S);

        S4(r0, 0)  S4(r1, 4)  S4(r2, 8)  S4(r3, 12)
        S4(r4, 16) S4(r5, 20) S4(r6, 24) S4(r7, 28)
    }
#undef L4
#undef S4

    // flush: per-wave rows into padded buf, block-reduce, write part[b,c]
    {
        float4* dst = (float4*)&buf[(wave * OUT_CAPS + lane) * FSTR];
#pragma unroll
        for (int q = 0; q < 8; ++q)
            dst[q] = make_float4(s[4 * q], s[4 * q + 1], s[4 * q + 2], s[4 * q + 3]);
    }
    __syncthreads();
    {
        float4* pb4 = (float4*)(part_out + ((size_t)b * NCHUNK + c) * OUT_CAPS * IN_LEN);
        for (int e = tid; e < OUT_CAPS * IN_LEN / 4; e += 256) {
            const int o = e >> 3, q4 = (e & 7) * 4;
            const float4 a0 = *(const float4*)&buf[(0 * OUT_CAPS + o) * FSTR + q4];
            const float4 a1 = *(const float4*)&buf[(1 * OUT_CAPS + o) * FSTR + q4];
            const float4 a2 = *(const float4*)&buf[(2 * OUT_CAPS + o) * FSTR + q4];
            const float4 a3 = *(const float4*)&buf[(3 * OUT_CAPS + o) * FSTR + q4];
            pb4[e] = make_float4(a0.x + a1.x + a2.x + a3.x,
                                 a0.y + a1.y + a2.y + a3.y,
                                 a0.z + a1.z + a2.z + a3.z,
                                 a0.w + a1.w + a2.w + a3.w);
        }
    }
}

// ---------------------------------------------------------------------------
// k_init: s0 = (1/64) sum_n x[b,n,:]; u = W@s0; squash; T = W^T@v0.
// 32 blocks x 512 threads; block d handles batch (d&7)*4+(d>>3) so the x
// slab it pulls from HBM lands in the XCD L2 (b/4 = d&7) that the pass
// kernels for batch b will run on.
// ---------------------------------------------------------------------------
__global__ __launch_bounds__(512) void k_init(const float* __restrict__ x,
                                              const float* __restrict__ W,
                                              float* __restrict__ T) {
    const int d   = blockIdx.x;
    const int b   = (d & 7) * 4 + (d >> 3);   // XCD-aligned batch
    const int tid = threadIdx.x;
    const float* xb = x + (size_t)b * IN_CAPS * IN_LEN;

    __shared__ float4 red4[64][8];            // 8 KB (R8-proven shape)
    {
        const int q = tid & 7;
        const int g = tid >> 3;               // 0..63
        float4 acc = make_float4(0.f, 0.f, 0.f, 0.f);
        for (int n = g; n < IN_CAPS; n += 64) {   // 18 independent loads
            const float4 v = *(const float4*)(xb + n * IN_LEN + q * 4);
            acc.x += v.x; acc.y += v.y; acc.z += v.z; acc.w += v.w;
        }
        red4[g][q] = acc;
    }
    __syncthreads();
    __shared__ float s0[IN_LEN];
    if (tid < 8) {
        float4 v = make_float4(0.f, 0.f, 0.f, 0.f);
#pragma unroll 16
        for (int g = 0; g < 64; ++g) {
            const float4 r = red4[g][tid];
            v.x += r.x; v.y += r.y; v.z += r.z; v.w += r.w;
        }
        const float inv = 1.f / 64.f;   // uniform softmax prob at r=0
        s0[tid * 4 + 0] = v.x * inv;
        s0[tid * 4 + 1] = v.y * inv;
        s0[tid * 4 + 2] = v.z * inv;
        s0[tid * 4 + 3] = v.w * inv;
    }
    __syncthreads();

    __shared__ float u[OUT_CAPS * OUT_LEN];
    for (int e = tid; e < OUT_CAPS * OUT_LEN; e += 512) {
        const float* wrow = W + (size_t)e * IN_LEN;
        float a = 0.f;
#pragma unroll
        for (int i = 0; i < IN_LEN; ++i) a = fmaf(wrow[i], s0[i], a);
        u[e] = a;
    }
    __syncthreads();

    __shared__ float scale[OUT_CAPS];
    if (tid < OUT_CAPS) {
        float ns = 0.f;
#pragma unroll
        for (int l = 0; l < OUT_LEN; ++l) { const float v = u[tid * OUT_LEN + l]; ns = fmaf(v, v, ns); }
        scale[tid] = sqrtf(ns) / (1.f + ns);
    }
    __syncthreads();

    for (int e = tid; e < OUT_CAPS * IN_LEN; e += 512) {
        const int o = e >> 5, i = e & 31;
        float a = 0.f;
#pragma unroll
        for (int l = 0; l < OUT_LEN; ++l)
            a = fmaf(W[((size_t)o * OUT_LEN + l) * IN_LEN + i], u[o * OUT_LEN + l], a);
        T[(size_t)b * OUT_CAPS * IN_LEN + e] = a * scale[o];
    }
}

// ---------------------------------------------------------------------------
// k_pass1: stage T[b] -> stride-33 LDS, then routing iter 1 -> part.
// (R12-proven)
// ---------------------------------------------------------------------------
__global__ __launch_bounds__(256, 2) void k_pass1(const float* __restrict__ x,
                                                  const float* __restrict__ T,
                                                  float* __restrict__ part) {
    DECODE_BC(blockIdx.x, b, c)
    const int tid  = threadIdx.x;
    const int lane = tid & 63;
    const int wave = __builtin_amdgcn_readfirstlane(tid >> 6);

    __shared__ float t_lds[OUT_CAPS * TSTR];                         // 8.25 KB
    __shared__ __align__(16) float buf[PASS_WAVES * OUT_CAPS * FSTR]; // 36 KB

    {
        const float* Tb = T + (size_t)b * OUT_CAPS * IN_LEN;
        for (int e = tid; e < OUT_CAPS * IN_LEN; e += 256)
            t_lds[(e >> 5) * TSTR + (e & 31)] = Tb[e];   // coalesced read, cf write
    }
    __syncthreads();

    pass_v2(x, t_lds, buf, part, b, c, tid, lane, wave);
}

// ---------------------------------------------------------------------------
// kB: redundant vt-reduce, wave-split (wave w sums slabs {w,w+4,w+8,w+12});
//     s -> u -> squash; T1 = T0 + W^T v1 into stride-33 LDS; then routing
//     iter 2 -> part2.
// ---------------------------------------------------------------------------
__global__ __launch_bounds__(256, 2) void kB(const float* __restrict__ x,
                                             const float* __restrict__ W,
                                             const float* __restrict__ T,
                                             const float* __restrict__ part,
                                             float* __restrict__ part2) {
    DECODE_BC(blockIdx.x, b, c)
    const int tid  = threadIdx.x;
    const int lane = tid & 63;
    const int wave = __builtin_amdgcn_readfirstlane(tid >> 6);

    __shared__ float t_lds[OUT_CAPS * TSTR];                          // 8.25 KB
    __shared__ __align__(16) float buf[PASS_WAVES * OUT_CAPS * FSTR]; // 36 KB

    float* uu = buf + 2048;   // 2048 floats (after combine, regions consumed)
    float* sc = buf + 4096;   // 64

    // ---- vt-reduce, wave-split: 4x memory parallelism, chain depth 8x4 ----
    {
        const float4* pb4 = (const float4*)(part + (size_t)b * NCHUNK * OUT_CAPS * IN_LEN);
        float4* wp = (float4*)buf + wave * 512;
        for (int e = lane; e < 512; e += 64) {
            float4 acc = make_float4(0.f, 0.f, 0.f, 0.f);
#pragma unroll
            for (int k = 0; k < 4; ++k) {
                const float4 v = pb4[(size_t)(wave + 4 * k) * 512 + e];
                acc.x += v.x; acc.y += v.y; acc.z += v.z; acc.w += v.w;
            }
            wp[e] = acc;
        }
    }
    __syncthreads();
    {
        float4* b4 = (float4*)buf;
        for (int e = tid; e < 512; e += 256) {
            const float4 a0 = b4[e], a1 = b4[512 + e], a2 = b4[1024 + e], a3 = b4[1536 + e];
            b4[e] = make_float4(a0.x + a1.x + a2.x + a3.x,
                                a0.y + a1.y + a2.y + a3.y,
                                a0.z + a1.z + a2.z + a3.z,
                                a0.w + a1.w + a2.w + a3.w);   // s -> buf[0..2048)
        }
    }
    __syncthreads();

    for (int e = tid; e < OUT_CAPS * OUT_LEN; e += 256) {
        const int o = e >> 5;
        const float* wrow = W + (size_t)e * IN_LEN;
        const float* srow = buf + o * IN_LEN;
        float a = 0.f;
#pragma unroll
        for (int i = 0; i < IN_LEN; ++i) a = fmaf(wrow[i], srow[i], a);
        uu[e] = a;
    }
    __syncthreads();
    if (tid < OUT_CAPS) {
        float ns = 0.f;
#pragma unroll
        for (int l = 0; l < OUT_LEN; ++l) { const float v = uu[tid * OUT_LEN + l]; ns = fmaf(v, v, ns); }
        sc[tid] = sqrtf(ns) / (1.f + ns);
    }
    __syncthreads();

    // T1 = T0 + W^T @ (uu * sc)  -> stride-33 LDS (conflict-free writes)
    for (int e = tid; e < OUT_CAPS * IN_LEN; e += 256) {
        const int o = e >> 5, i = e & 31;
        float a = 0.f;
#pragma unroll
        for (int l = 0; l < OUT_LEN; ++l)
            a = fmaf(W[((size_t)o * OUT_LEN + l) * IN_LEN + i], uu[o * OUT_LEN + l], a);
        t_lds[o * TSTR + i] = T[(size_t)b * OUT_CAPS * IN_LEN + e] + a * sc[o];
    }
    __syncthreads();

    pass_v2(x, t_lds, buf, part2, b, c, tid, lane, wave);
}

// ---------------------------------------------------------------------------
// kC: final vt, split by o-group, XCD-aligned: b=(d&7)*4+((d>>3)&3), og=d>>5
// so part2[b] (in XCD b/4's L2) is read by a block on that XCD.
// ---------------------------------------------------------------------------
__global__ __launch_bounds__(256) void kC(const float* __restrict__ W,
                                          const float* __restrict__ part2,
                                          float* __restrict__ out) {
    const int d   = blockIdx.x;
    const int b   = (d & 7) * 4 + ((d >> 3) & 3);
    const int og  = d >> 5;              // 0..7
    const int tid = threadIdx.x;
    const int ol  = tid >> 5;            // 0..7 local o
    const int i   = tid & 31;            // input index / later l
    const int o   = og * 8 + ol;

    float a = 0.f;
    const float* pb = part2 + (size_t)b * NCHUNK * OUT_CAPS * IN_LEN + o * IN_LEN + i;
#pragma unroll
    for (int cc = 0; cc < NCHUNK; ++cc) a += pb[cc * OUT_CAPS * IN_LEN];

    __shared__ float s_lds[8][33];
    s_lds[ol][i] = a;
    __syncthreads();

    const float* wrow = W + ((size_t)o * OUT_LEN + i) * IN_LEN;
    float u = 0.f;
#pragma unroll
    for (int k = 0; k < IN_LEN; ++k) u = fmaf(wrow[k], s_lds[ol][k], u);

    float ns = u * u;
    ns += __shfl_xor(ns, 1, 64);
    ns += __shfl_xor(ns, 2, 64);
    ns += __shfl_xor(ns, 4, 64);
    ns += __shfl_xor(ns, 8, 64);
    ns += __shfl_xor(ns, 16, 64);
    const float scale = sqrtf(ns) / (1.f + ns);

    out[((size_t)b * OUT_CAPS + o) * OUT_LEN + i] = u * scale;
}

extern "C" void kernel_launch(void* const* d_in, const int* in_sizes, int n_in,
                              void* d_out, int out_size, void* d_ws, size_t ws_size,
                              hipStream_t stream) {
    const float* x = (const float*)d_in[0];   // [32,1152,32]
    const float* W = (const float*)d_in[1];   // [64,32,32]
    float* out = (float*)d_out;               // [32,64,32]

    float* T     = (float*)d_ws;                          // 256 KB
    float* part  = T + (size_t)N_B * OUT_CAPS * IN_LEN;   // 4 MB (iter-1 partials)
    float* part2 = part + (size_t)N_B * NCHUNK * OUT_CAPS * IN_LEN; // 4 MB (iter-2)

    k_init <<<N_B,          512, 0, stream>>>(x, W, T);
    k_pass1<<<N_B * NCHUNK, 256, 0, stream>>>(x, T, part);           // iter 1
    kB     <<<N_B * NCHUNK, 256, 0, stream>>>(x, W, T, part, part2); // vt1 + iter 2
    kC     <<<N_B * 8,      256, 0, stream>>>(W, part2, out);        // final vt
}